// Round 22
// baseline (294.391 us; speedup 1.0000x reference)
//
#include <hip/hip_runtime.h>
#include <hip/hip_bf16.h>
#include <math.h>

#define NB 2
#define NS 2048
#define ND 2048
#define NH 16
#define DNOPE 128
#define DROPE 64
#define DVAL 128
#define RANK 512
#define QW (NH*(DNOPE+DROPE))    // 3072
#define AW (RANK+DROPE)          // 576
#define AWPAD 640
#define BW (NH*(DNOPE+DVAL))     // 4096
#define OW (NH*DVAL)             // 2048
#define ATT_SCALE2 0.10411758590510176f   // (192)^-0.5 * log2(e), folded into q
#define LOG2_10000 13.287712379549449f

typedef __attribute__((ext_vector_type(8))) short short8;
typedef __attribute__((ext_vector_type(4))) float f32x4;

__device__ __forceinline__ float b2f(unsigned short u) {
  unsigned x = ((unsigned)u) << 16; float f; __builtin_memcpy(&f, &x, 4); return f;
}
__device__ __forceinline__ unsigned short f2b(float f) {
  unsigned x; __builtin_memcpy(&x, &f, 4);
  unsigned r = (x + 0x7fffu + ((x >> 16) & 1u)) >> 16;
  return (unsigned short)r;
}
__device__ __forceinline__ unsigned cvtpk(float a, float b) {
  unsigned r;
  asm("v_cvt_pk_bf16_f32 %0, %1, %2" : "=v"(r) : "v"(a), "v"(b));
  return r;
}
__device__ __forceinline__ void gload16(const void* g, void* lds) {
  __builtin_amdgcn_global_load_lds((const __attribute__((address_space(1))) void*)g,
                                   (__attribute__((address_space(3))) void*)lds, 16, 0, 0);
}

// ---------- fp32 -> bf16 flat convert ----------
__global__ __launch_bounds__(256) void k_cvt(const float* __restrict__ X,
                                             unsigned short* __restrict__ Y) {
  long i = ((long)blockIdx.x * 256 + threadIdx.x) * 4;
  float4 v = *(const float4*)(X + i);
  ushort4 o;
  o.x = f2b(v.x); o.y = f2b(v.y); o.z = f2b(v.z); o.w = f2b(v.w);
  *(ushort4*)(Y + i) = o;
}

// ---------- transpose+convert: W fp32 [K][N] -> WT bf16 [Npad][K], zero pad ----------
__global__ __launch_bounds__(256) void k_transpose(const float* __restrict__ W,
                                                   unsigned short* __restrict__ WT,
                                                   int K, int N) {
  __shared__ float t[32][33];
  const int k0 = blockIdx.x * 32, n0 = blockIdx.y * 32;
  const int tx = threadIdx.x & 31, ty = threadIdx.x >> 5;
  #pragma unroll
  for (int i = 0; i < 32; i += 8) {
    int n = n0 + tx;
    float v = (n < N) ? W[(size_t)(k0 + ty + i) * N + n] : 0.f;
    t[ty + i][tx] = v;
  }
  __syncthreads();
  #pragma unroll
  for (int i = 0; i < 32; i += 8)
    WT[(size_t)(n0 + ty + i) * K + k0 + tx] = f2b(t[tx][ty + i]);
}

// ---------- bf16 MFMA GEMM (validated round 6; + XCD swizzle) ----------
template <typename OutT>
__global__ __launch_bounds__(256) void gemm_bf16(
    const unsigned short* __restrict__ A, const unsigned short* __restrict__ BT,
    OutT* __restrict__ C, int M, int N, int K, int lda) {
  __shared__ short8 AsV[1024];
  __shared__ short8 BsV[1024];
  const int tid = threadIdx.x;
  const int l = tid & 63, w = tid >> 6;
  const int nwg = gridDim.x * gridDim.y;
  const int bid = blockIdx.y * gridDim.x + blockIdx.x;
  const int sbid = (bid & 7) * (nwg >> 3) + (bid >> 3);
  const int bx = sbid % gridDim.x, by = sbid / gridDim.x;
  const int bm = by * 128, bn = bx * 128;
  const int wm = (w >> 1) * 64, wn = (w & 1) * 64;
  f32x4 acc[4][4] = {};

  const int srow = tid >> 3;
  const int gk   = ((((tid & 7) * 16) ^ ((srow & 7) << 4)) >> 1);
  const int sw   = l & 7;

  for (int k0 = 0; k0 < K; k0 += 64) {
    #pragma unroll
    for (int i = 0; i < 4; ++i) {
      const int row = i * 32 + srow;
      gload16(A + (size_t)(bm + row) * lda + k0 + gk, (char*)AsV + i * 4096 + w * 1024);
      gload16(BT + (size_t)(bn + row) * K   + k0 + gk, (char*)BsV + i * 4096 + w * 1024);
    }
    __syncthreads();
    #pragma unroll
    for (int kk2 = 0; kk2 < 2; ++kk2) {
      const int kb = kk2 * 4 + (l >> 4);
      short8 af[4], bg[4];
      #pragma unroll
      for (int mi = 0; mi < 4; ++mi)
        af[mi] = AsV[(wm + mi * 16 + (l & 15)) * 8 + (kb ^ sw)];
      #pragma unroll
      for (int ni = 0; ni < 4; ++ni)
        bg[ni] = BsV[(wn + ni * 16 + (l & 15)) * 8 + (kb ^ sw)];
      #pragma unroll
      for (int mi = 0; mi < 4; ++mi)
        #pragma unroll
        for (int ni = 0; ni < 4; ++ni)
          acc[mi][ni] = __builtin_amdgcn_mfma_f32_16x16x32_bf16(af[mi], bg[ni], acc[mi][ni], 0, 0, 0);
    }
    __syncthreads();
  }

  const int r0 = bm + wm + (l >> 4) * 4;
  const int c0 = bn + wn + (l & 15);
  #pragma unroll
  for (int mi = 0; mi < 4; ++mi)
    #pragma unroll
    for (int ni = 0; ni < 4; ++ni) {
      const int col = c0 + ni * 16;
      if (col < N) {
        #pragma unroll
        for (int j = 0; j < 4; ++j) {
          float v = acc[mi][ni][j];
          if constexpr (__is_same(OutT, float))
            C[(size_t)(r0 + mi * 16 + j) * N + col] = v;
          else
            C[(size_t)(r0 + mi * 16 + j) * N + col] = f2b(v);
        }
      }
    }
}

// ---------- fused q+kva GEMM: N = 3712; q cols pre-scaled by ATT_SCALE2 ----------
__global__ __launch_bounds__(256) void gemm_fused_qkva(
    const unsigned short* __restrict__ A, const unsigned short* __restrict__ BT,
    unsigned short* __restrict__ Cq, unsigned short* __restrict__ Ckva, int K) {
  __shared__ short8 AsV[1024];
  __shared__ short8 BsV[1024];
  const int tid = threadIdx.x;
  const int l = tid & 63, w = tid >> 6;
  const int nwg = gridDim.x * gridDim.y;
  const int bid = blockIdx.y * gridDim.x + blockIdx.x;
  const int sbid = (bid & 7) * (nwg >> 3) + (bid >> 3);
  const int bx = sbid % gridDim.x, by = sbid / gridDim.x;
  const int bm = by * 128, bn = bx * 128;
  const int wm = (w >> 1) * 64, wn = (w & 1) * 64;
  f32x4 acc[4][4] = {};

  const int srow = tid >> 3;
  const int gk   = ((((tid & 7) * 16) ^ ((srow & 7) << 4)) >> 1);
  const int sw   = l & 7;

  for (int k0 = 0; k0 < K; k0 += 64) {
    #pragma unroll
    for (int i = 0; i < 4; ++i) {
      const int row = i * 32 + srow;
      gload16(A + (size_t)(bm + row) * K + k0 + gk, (char*)AsV + i * 4096 + w * 1024);
      gload16(BT + (size_t)(bn + row) * K + k0 + gk, (char*)BsV + i * 4096 + w * 1024);
    }
    __syncthreads();
    #pragma unroll
    for (int kk2 = 0; kk2 < 2; ++kk2) {
      const int kb = kk2 * 4 + (l >> 4);
      short8 af[4], bg[4];
      #pragma unroll
      for (int mi = 0; mi < 4; ++mi)
        af[mi] = AsV[(wm + mi * 16 + (l & 15)) * 8 + (kb ^ sw)];
      #pragma unroll
      for (int ni = 0; ni < 4; ++ni)
        bg[ni] = BsV[(wn + ni * 16 + (l & 15)) * 8 + (kb ^ sw)];
      #pragma unroll
      for (int mi = 0; mi < 4; ++mi)
        #pragma unroll
        for (int ni = 0; ni < 4; ++ni)
          acc[mi][ni] = __builtin_amdgcn_mfma_f32_16x16x32_bf16(af[mi], bg[ni], acc[mi][ni], 0, 0, 0);
    }
    __syncthreads();
  }

  const int r0 = bm + wm + (l >> 4) * 4;
  const int c0 = bn + wn + (l & 15);
  #pragma unroll
  for (int mi = 0; mi < 4; ++mi)
    #pragma unroll
    for (int ni = 0; ni < 4; ++ni) {
      const int col = c0 + ni * 16;
      #pragma unroll
      for (int j = 0; j < 4; ++j) {
        const float v = acc[mi][ni][j];
        const int row = r0 + mi * 16 + j;
        if (col < QW)
          Cq[(size_t)row * QW + col] = f2b(v * ATT_SCALE2);  // fold softmax scale
        else if (col - QW < AW)
          Ckva[(size_t)row * AW + (col - QW)] = f2b(v);
      }
    }
}

// ---------- fused RMSNorm(cols 0..511) + RoPE-k(cols 512..575), one wave per row ----------
__global__ __launch_bounds__(64) void k_rms_ropek(unsigned short* __restrict__ kva,
                                                  const float* __restrict__ w) {
  const int row = blockIdx.x;
  const int t = row & (NS - 1);
  const int lane = threadIdx.x;
  unsigned short* p = kva + (long)row * AW;

  short8 v = *(const short8*)(p + lane * 8);
  float f[8];
  float ss = 0.f;
  #pragma unroll
  for (int j = 0; j < 8; ++j) {
    f[j] = b2f((unsigned short)v[j]);
    ss += f[j] * f[j];
  }
  #pragma unroll
  for (int o2 = 1; o2 < 64; o2 <<= 1) ss += __shfl_xor(ss, o2, 64);
  const float sc = rsqrtf(ss / (float)RANK + 1e-6f);
  short8 ov;
  #pragma unroll
  for (int j = 0; j < 8; ++j)
    ov[j] = (short)f2b(f[j] * sc * w[lane * 8 + j]);
  *(short8*)(p + lane * 8) = ov;

  if (lane < 32) {
    const float invf = exp2f(-(float)lane * (LOG2_10000 / 32.0f));
    const float ang = (float)t * invf;
    float s, c;
    sincosf(ang, &s, &c);
    unsigned short* pp = p + RANK + 2 * lane;
    const float x0 = b2f(pp[0]), x1 = b2f(pp[1]);
    pp[0] = f2b(x0 * c - x1 * s);
    pp[1] = f2b(x0 * s + x1 * c);
  }
}

// ---------- MFMA flash attention: Ks dbuf, one barrier/tile, rope-q fused ----------
// grid (8, NH, NB), 512 thr = 8 waves x 16 rows, q-tile pairs (bx, 15-bx) -> 34 tiles/block.
// Softmax scale pre-folded into q (fused-qkva epilogue) -> S arrives scaled.
#define KBLK 64
#define KSL 24               // 16B slots per K row (192 bf16)
#define KSB (KBLK*KSL*16)    // one Ks buffer, bytes (24 KB)
#define VTS 72               // VT row stride (elems)
#define VBUF (DVAL*VTS)      // one VT buffer (elems)
#define PLS 72               // P row stride (elems)
#define QTILES (NS/128)      // 16
__global__ __launch_bounds__(512) void k_attn_mfma(
    const unsigned short* __restrict__ qg,
    const unsigned short* __restrict__ kvbg,
    const unsigned short* __restrict__ kvag,
    unsigned short* __restrict__ attg) {
  __shared__ short8 Ks[2 * KBLK * KSL];                        // 48 KB (dbuf)
  __shared__ __align__(16) unsigned short VT[2 * VBUF];        // 36 KB (dbuf)
  __shared__ __align__(16) unsigned short Pl[128 * PLS];       // 18 KB
  const int tid = threadIdx.x;
  const int l = tid & 63, w = tid >> 6;    // w 0..7
  const int g = l >> 4, r16 = l & 15;
  const int h = blockIdx.y;
  const int b = blockIdx.z;
  const unsigned short* q   = qg   + (size_t)b * NS * QW;
  const unsigned short* kvb = kvbg + (size_t)b * NS * BW;
  const unsigned short* kva = kvag + (size_t)b * NS * AW;
  unsigned short* att = attg + (size_t)b * NS * OW;

  // ---- staging geometry, constant per thread ----
  const unsigned short* kbs[3]; int kstp[3]; int kdo[3];
  #pragma unroll
  for (int i = 0; i < 3; ++i) {
    const int chunk = i * 512 + tid;
    const int row = chunk / KSL, p = chunk % KSL;
    const int s = (p & ~7) | ((p & 7) ^ (row & 7));
    const int d0 = s * 8;
    if (d0 < DNOPE) { kbs[i] = kvb + (size_t)row * BW + h * 256 + d0; kstp[i] = KBLK * BW; }
    else            { kbs[i] = kva + (size_t)row * AW + RANK + (d0 - DNOPE); kstp[i] = KBLK * AW; }
    kdo[i] = (i * 512 + (tid & ~63)) * 16;
  }
  const int vt_t = tid >> 3, vqd = tid & 7;
  const unsigned short* vbs = kvb + (size_t)vt_t * BW + h * 256 + DNOPE + vqd * 8;
  unsigned short* vwd = VT + (vqd * 8) * VTS + (vt_t ^ (vqd << 3));

  #pragma unroll 1
  for (int phase = 0; phase < 2; ++phase) {
    const int qt = phase ? (QTILES - 1 - (int)blockIdx.x) : (int)blockIdx.x;
    const int nt = 2 * qt + 2;
    const int qrow0 = qt * 128 + w * 16;

    // Q A-frags with fused RoPE on pe frags (f = 4,5); q already carries ATT_SCALE2
    short8 aq[6];
    {
      const unsigned short* qp = q + (size_t)(qrow0 + r16) * QW + h * 192 + g * 8;
      const float tpos = (float)(qrow0 + r16);
      #pragma unroll
      for (int f = 0; f < 6; ++f) {
        short8 v = *(const short8*)(qp + f * 32);
        if (f >= 4) {
          const int ibase = (f - 4) * 16 + g * 4;
          #pragma unroll
          for (int m = 0; m < 4; ++m) {
            const float invf = exp2f(-(float)(ibase + m) * (LOG2_10000 / 32.0f));
            float s_, c_;
            sincosf(tpos * invf, &s_, &c_);
            const float x0 = b2f((unsigned short)v[2 * m]);
            const float x1 = b2f((unsigned short)v[2 * m + 1]);
            v[2 * m]     = (short)f2b(x0 * c_ - x1 * s_);
            v[2 * m + 1] = (short)f2b(x0 * s_ + x1 * c_);
          }
        }
        aq[f] = v;
      }
    }
    f32x4 o[8] = {};
    float m_j[4], l_j[4];     // m_j: wave-uniform per row; l_j: LANE-PARTIAL sums
    #pragma unroll
    for (int j = 0; j < 4; ++j) { m_j[j] = -1e30f; l_j[j] = 0.f; }

    const unsigned short* kq0 = kbs[0];
    const unsigned short* kq1 = kbs[1];
    const unsigned short* kq2 = kbs[2];
    const unsigned short* vq  = vbs;

    // prologue: stage K_0 + V_0 into buffer 0
    gload16(kq0, (char*)Ks + kdo[0]); kq0 += kstp[0];
    gload16(kq1, (char*)Ks + kdo[1]); kq1 += kstp[1];
    gload16(kq2, (char*)Ks + kdo[2]); kq2 += kstp[2];
    {
      short8 vA = *(const short8*)(vq);
      short8 vB = *(const short8*)(vq + 64);
      #pragma unroll
      for (int jj = 0; jj < 8; ++jj) {
        vwd[jj * VTS] = (unsigned short)vA[jj];
        vwd[64 * VTS + jj * VTS] = (unsigned short)vB[jj];
      }
      vq += KBLK * BW;
    }
    __syncthreads();
    int cur = 0;

    for (int kt = 0; kt < nt; ++kt) {
      // (a) issue next-tile prefetch EARLY: K -> Ks[cur^1] (async), V -> regs
      const bool pref = (kt + 1 < nt);
      short8 vA, vB;
      if (pref) {
        char* kb1 = (char*)Ks + (cur ^ 1) * KSB;
        gload16(kq0, kb1 + kdo[0]); kq0 += kstp[0];
        gload16(kq1, kb1 + kdo[1]); kq1 += kstp[1];
        gload16(kq2, kb1 + kdo[2]); kq2 += kstp[2];
        vA = *(const short8*)(vq);
        vB = *(const short8*)(vq + 64);
        vq += KBLK * BW;
      }

      // (b) S = Q K^T from Ks[cur]  (already scaled via q)
      const short8* ksrc = Ks + cur * (KBLK * KSL);
      f32x4 sa[4] = {};
      __builtin_amdgcn_s_setprio(1);
      #pragma unroll
      for (int f = 0; f < 6; ++f) {
        #pragma unroll
        for (int n = 0; n < 4; ++n) {
          const int row = n * 16 + r16;
          const int s = f * 4 + g;
          const int phys = (s & ~7) | ((s & 7) ^ (row & 7));
          short8 bg = ksrc[row * KSL + phys];
          sa[n] = __builtin_amdgcn_mfma_f32_16x16x32_bf16(aq[f], bg, sa[n], 0, 0, 0);
        }
      }
      __builtin_amdgcn_s_setprio(0);

      // (c) softmax (log2 domain), lazy-max, lane-partial l
      const bool diag = (kt >= nt - 2);
      float pj[4][4];
      #pragma unroll
      for (int n = 0; n < 4; ++n) {
        const int key = kt * KBLK + n * 16 + r16;
        #pragma unroll
        for (int j = 0; j < 4; ++j) {
          float v = sa[n][j];
          if (diag && key > (qrow0 + g * 4 + j)) v = -1e30f;
          pj[n][j] = v;
        }
      }
      float mjl[4];
      #pragma unroll
      for (int j = 0; j < 4; ++j)
        mjl[j] = fmaxf(fmaxf(pj[0][j], pj[1][j]), fmaxf(pj[2][j], pj[3][j]));
      const bool myneed = (mjl[0] > m_j[0] + 8.f) | (mjl[1] > m_j[1] + 8.f) |
                          (mjl[2] > m_j[2] + 8.f) | (mjl[3] > m_j[3] + 8.f);
      if (__any(myneed)) {             // rare after first tile
        #pragma unroll
        for (int j = 0; j < 4; ++j) {
          float mx = mjl[j];
          #pragma unroll
          for (int o2 = 1; o2 < 16; o2 <<= 1) mx = fmaxf(mx, __shfl_xor(mx, o2, 64));
          const float mn = fmaxf(m_j[j], mx);
          const float c = exp2f(m_j[j] - mn);
          l_j[j] *= c;
          #pragma unroll
          for (int n8 = 0; n8 < 8; ++n8) o[n8][j] *= c;
          m_j[j] = mn;
        }
      }
      #pragma unroll
      for (int j = 0; j < 4; ++j) {
        float p0 = exp2f(pj[0][j] - m_j[j]);
        float p1 = exp2f(pj[1][j] - m_j[j]);
        float p2 = exp2f(pj[2][j] - m_j[j]);
        float p3 = exp2f(pj[3][j] - m_j[j]);
        l_j[j] += (p0 + p1) + (p2 + p3);   // lane-partial; reduced in epilogue
        const int prow = w * 16 + g * 4 + j;
        const int cswz = r16 ^ ((g >> 1) << 3);    // col bit3 ^= row bit3
        const unsigned pk01 = cvtpk(p0, p1);
        const unsigned pk23 = cvtpk(p2, p3);
        Pl[prow * PLS +  0 + cswz] = (unsigned short)pk01;
        Pl[prow * PLS + 16 + cswz] = (unsigned short)(pk01 >> 16);
        Pl[prow * PLS + 32 + cswz] = (unsigned short)pk23;
        Pl[prow * PLS + 48 + cswz] = (unsigned short)(pk23 >> 16);
      }

      // (d) write prefetched V into the alternate buffer
      if (pref) {
        unsigned short* dst = vwd + (cur ^ 1) * VBUF;
        #pragma unroll
        for (int jj = 0; jj < 8; ++jj) {
          dst[jj * VTS] = (unsigned short)vA[jj];
          dst[64 * VTS + jj * VTS] = (unsigned short)vB[jj];
        }
      }

      // (e) O += P V from VT[cur]  (Pl rows wave-private; read block ^= r16>>3)
      const int hb = r16 >> 3;
      const unsigned short* vbase = VT + cur * VBUF;
      #pragma unroll
      for (int kk = 0; kk < 2; ++kk) {
        short8 pa = *(const short8*)&Pl[(w * 16 + r16) * PLS +
                                        ((((kk * 4 + g) ^ hb) & 7) << 3)];
        __builtin_amdgcn_s_setprio(1);
        #pragma unroll
        for (int n8 = 0; n8 < 8; ++n8) {
          const int blk = (kk * 4 + g) ^ ((n8 * 2 + hb) & 7);
          short8 vb = *(const short8*)&vbase[(n8 * 16 + r16) * VTS + blk * 8];
          o[n8] = __builtin_amdgcn_mfma_f32_16x16x32_bf16(pa, vb, o[n8], 0, 0, 0);
        }
        __builtin_amdgcn_s_setprio(0);
      }

      // (f) single barrier: K_{t+1} gloads drained, VT[cur^1] writes visible
      __syncthreads();
      cur ^= 1;
    }

    // epilogue: reduce lane-partial l across the 16 lanes of each row, then store
    #pragma unroll
    for (int j = 0; j < 4; ++j) {
      float ls = l_j[j];
      #pragma unroll
      for (int o2 = 1; o2 < 16; o2 <<= 1) ls += __shfl_xor(ls, o2, 64);
      const float inv = 1.0f / ls;
      const size_t rowoff = (size_t)(qrow0 + g * 4 + j) * OW + h * DVAL;
      #pragma unroll
      for (int n8 = 0; n8 < 8; ++n8)
        att[rowoff + n8 * 16 + r16] = f2b(o[n8][j] * inv);
    }
    __syncthreads();                   // protect next phase's prologue staging
  }
}

extern "C" void kernel_launch(void* const* d_in, const int* in_sizes, int n_in,
                              void* d_out, int out_size, void* d_ws, size_t ws_size,
                              hipStream_t stream) {
  const float* x      = (const float*)d_in[0];
  const float* wq     = (const float*)d_in[1];
  const float* wkv_a  = (const float*)d_in[2];
  const float* w_norm = (const float*)d_in[3];
  const float* wkv_b  = (const float*)d_in[4];
  const float* wo     = (const float*)d_in[5];
  float* out = (float*)d_out;

  unsigned short* wqT   = (unsigned short*)d_ws;           // 3072 x 2048
  unsigned short* wkvaT = wqT   + (long)QW * ND;           // 640  x 2048 (contiguous after wqT)
  unsigned short* wkvbT = wkvaT + (long)AWPAD * ND;        // 4096 x 512
  unsigned short* woT   = wkvbT + (long)BW * RANK;         // 2048 x 2048
  unsigned short* xb2   = woT   + (long)ND * OW;           // 2 x 2048 x 2048
  unsigned short* q2    = xb2   + (long)NB * NS * ND;      // 2 x 2048 x 3072
  unsigned short* kva2  = q2    + (long)NB * NS * QW;      // 2 x 2048 x 576
  unsigned short* kvb2  = kva2  + (long)NB * NS * AW;      // 2 x 2048 x 4096
  unsigned short* att2  = xb2;                             // alias (xb2 dead by attn)

  k_transpose<<<dim3(ND / 32, QW / 32),    dim3(256), 0, stream>>>(wq,    wqT,   ND,  QW);
  k_transpose<<<dim3(ND / 32, AWPAD / 32), dim3(256), 0, stream>>>(wkv_a, wkvaT, ND,  AW);
  k_transpose<<<dim3(RANK / 32, BW / 32),  dim3(256), 0, stream>>>(wkv_b, wkvbT, RANK, BW);
  k_transpose<<<dim3(OW / 32, ND / 32),    dim3(256), 0, stream>>>(wo,    woT,   OW,  ND);

  k_cvt<<<dim3((NB * NS * ND) / 1024), dim3(256), 0, stream>>>(x, xb2);
  gemm_fused_qkva<<<dim3((QW + AWPAD) / 128, (NB * NS) / 128), dim3(256), 0, stream>>>(
      xb2, wqT, q2, kva2, ND);
  k_rms_ropek<<<dim3(NB * NS), dim3(64), 0, stream>>>(kva2, w_norm);
  gemm_bf16<unsigned short><<<dim3(BW / 128, (NB * NS) / 128), dim3(256), 0, stream>>>(
      kva2, wkvbT, kvb2, NB * NS, BW, RANK, AW);
  k_attn_mfma<<<dim3(QTILES / 2, NH, NB), dim3(512), 0, stream>>>(q2, kvb2, kva2, att2);
  gemm_bf16<float><<<dim3(ND / 128, (NB * NS) / 128), dim3(256), 0, stream>>>(
      att2, woT, out, NB * NS, ND, OW, OW);
}

// Round 23
// 287.331 us; speedup vs baseline: 1.0246x; 1.0246x over previous
//
#include <hip/hip_runtime.h>
#include <hip/hip_bf16.h>
#include <math.h>

#define NB 2
#define NS 2048
#define ND 2048
#define NH 16
#define DNOPE 128
#define DROPE 64
#define DVAL 128
#define RANK 512
#define QW (NH*(DNOPE+DROPE))    // 3072
#define AW (RANK+DROPE)          // 576
#define AWPAD 640
#define BW (NH*(DNOPE+DVAL))     // 4096
#define OW (NH*DVAL)             // 2048
#define ATT_SCALE2 0.10411758590510176f   // (192)^-0.5 * log2(e), folded into q
#define LOG2_10000 13.287712379549449f

typedef __attribute__((ext_vector_type(8))) short short8;
typedef __attribute__((ext_vector_type(4))) float f32x4;

__device__ __forceinline__ float b2f(unsigned short u) {
  unsigned x = ((unsigned)u) << 16; float f; __builtin_memcpy(&f, &x, 4); return f;
}
__device__ __forceinline__ unsigned short f2b(float f) {
  unsigned x; __builtin_memcpy(&x, &f, 4);
  unsigned r = (x + 0x7fffu + ((x >> 16) & 1u)) >> 16;
  return (unsigned short)r;
}
__device__ __forceinline__ unsigned cvtpk(float a, float b) {
  unsigned r;
  asm("v_cvt_pk_bf16_f32 %0, %1, %2" : "=v"(r) : "v"(a), "v"(b));
  return r;
}
__device__ __forceinline__ void gload16(const void* g, void* lds) {
  __builtin_amdgcn_global_load_lds((const __attribute__((address_space(1))) void*)g,
                                   (__attribute__((address_space(3))) void*)lds, 16, 0, 0);
}

// ---------- fp32 -> bf16 flat convert ----------
__global__ __launch_bounds__(256) void k_cvt(const float* __restrict__ X,
                                             unsigned short* __restrict__ Y) {
  long i = ((long)blockIdx.x * 256 + threadIdx.x) * 4;
  float4 v = *(const float4*)(X + i);
  ushort4 o;
  o.x = f2b(v.x); o.y = f2b(v.y); o.z = f2b(v.z); o.w = f2b(v.w);
  *(ushort4*)(Y + i) = o;
}

// ---------- transpose+convert: W fp32 [K][N] -> WT bf16 [Npad][K], zero pad ----------
__global__ __launch_bounds__(256) void k_transpose(const float* __restrict__ W,
                                                   unsigned short* __restrict__ WT,
                                                   int K, int N) {
  __shared__ float t[32][33];
  const int k0 = blockIdx.x * 32, n0 = blockIdx.y * 32;
  const int tx = threadIdx.x & 31, ty = threadIdx.x >> 5;
  #pragma unroll
  for (int i = 0; i < 32; i += 8) {
    int n = n0 + tx;
    float v = (n < N) ? W[(size_t)(k0 + ty + i) * N + n] : 0.f;
    t[ty + i][tx] = v;
  }
  __syncthreads();
  #pragma unroll
  for (int i = 0; i < 32; i += 8)
    WT[(size_t)(n0 + ty + i) * K + k0 + tx] = f2b(t[tx][ty + i]);
}

// ---------- bf16 MFMA GEMM (validated round 6; + XCD swizzle) ----------
template <typename OutT>
__global__ __launch_bounds__(256) void gemm_bf16(
    const unsigned short* __restrict__ A, const unsigned short* __restrict__ BT,
    OutT* __restrict__ C, int M, int N, int K, int lda) {
  __shared__ short8 AsV[1024];
  __shared__ short8 BsV[1024];
  const int tid = threadIdx.x;
  const int l = tid & 63, w = tid >> 6;
  const int nwg = gridDim.x * gridDim.y;
  const int bid = blockIdx.y * gridDim.x + blockIdx.x;
  const int sbid = (bid & 7) * (nwg >> 3) + (bid >> 3);
  const int bx = sbid % gridDim.x, by = sbid / gridDim.x;
  const int bm = by * 128, bn = bx * 128;
  const int wm = (w >> 1) * 64, wn = (w & 1) * 64;
  f32x4 acc[4][4] = {};

  const int srow = tid >> 3;
  const int gk   = ((((tid & 7) * 16) ^ ((srow & 7) << 4)) >> 1);
  const int sw   = l & 7;

  for (int k0 = 0; k0 < K; k0 += 64) {
    #pragma unroll
    for (int i = 0; i < 4; ++i) {
      const int row = i * 32 + srow;
      gload16(A + (size_t)(bm + row) * lda + k0 + gk, (char*)AsV + i * 4096 + w * 1024);
      gload16(BT + (size_t)(bn + row) * K   + k0 + gk, (char*)BsV + i * 4096 + w * 1024);
    }
    __syncthreads();
    #pragma unroll
    for (int kk2 = 0; kk2 < 2; ++kk2) {
      const int kb = kk2 * 4 + (l >> 4);
      short8 af[4], bg[4];
      #pragma unroll
      for (int mi = 0; mi < 4; ++mi)
        af[mi] = AsV[(wm + mi * 16 + (l & 15)) * 8 + (kb ^ sw)];
      #pragma unroll
      for (int ni = 0; ni < 4; ++ni)
        bg[ni] = BsV[(wn + ni * 16 + (l & 15)) * 8 + (kb ^ sw)];
      #pragma unroll
      for (int mi = 0; mi < 4; ++mi)
        #pragma unroll
        for (int ni = 0; ni < 4; ++ni)
          acc[mi][ni] = __builtin_amdgcn_mfma_f32_16x16x32_bf16(af[mi], bg[ni], acc[mi][ni], 0, 0, 0);
    }
    __syncthreads();
  }

  const int r0 = bm + wm + (l >> 4) * 4;
  const int c0 = bn + wn + (l & 15);
  #pragma unroll
  for (int mi = 0; mi < 4; ++mi)
    #pragma unroll
    for (int ni = 0; ni < 4; ++ni) {
      const int col = c0 + ni * 16;
      if (col < N) {
        #pragma unroll
        for (int j = 0; j < 4; ++j) {
          float v = acc[mi][ni][j];
          if constexpr (__is_same(OutT, float))
            C[(size_t)(r0 + mi * 16 + j) * N + col] = v;
          else
            C[(size_t)(r0 + mi * 16 + j) * N + col] = f2b(v);
        }
      }
    }
}

// ---------- fused q+kva GEMM: N = 3712; q cols pre-scaled by ATT_SCALE2 ----------
__global__ __launch_bounds__(256) void gemm_fused_qkva(
    const unsigned short* __restrict__ A, const unsigned short* __restrict__ BT,
    unsigned short* __restrict__ Cq, unsigned short* __restrict__ Ckva, int K) {
  __shared__ short8 AsV[1024];
  __shared__ short8 BsV[1024];
  const int tid = threadIdx.x;
  const int l = tid & 63, w = tid >> 6;
  const int nwg = gridDim.x * gridDim.y;
  const int bid = blockIdx.y * gridDim.x + blockIdx.x;
  const int sbid = (bid & 7) * (nwg >> 3) + (bid >> 3);
  const int bx = sbid % gridDim.x, by = sbid / gridDim.x;
  const int bm = by * 128, bn = bx * 128;
  const int wm = (w >> 1) * 64, wn = (w & 1) * 64;
  f32x4 acc[4][4] = {};

  const int srow = tid >> 3;
  const int gk   = ((((tid & 7) * 16) ^ ((srow & 7) << 4)) >> 1);
  const int sw   = l & 7;

  for (int k0 = 0; k0 < K; k0 += 64) {
    #pragma unroll
    for (int i = 0; i < 4; ++i) {
      const int row = i * 32 + srow;
      gload16(A + (size_t)(bm + row) * K + k0 + gk, (char*)AsV + i * 4096 + w * 1024);
      gload16(BT + (size_t)(bn + row) * K + k0 + gk, (char*)BsV + i * 4096 + w * 1024);
    }
    __syncthreads();
    #pragma unroll
    for (int kk2 = 0; kk2 < 2; ++kk2) {
      const int kb = kk2 * 4 + (l >> 4);
      short8 af[4], bg[4];
      #pragma unroll
      for (int mi = 0; mi < 4; ++mi)
        af[mi] = AsV[(wm + mi * 16 + (l & 15)) * 8 + (kb ^ sw)];
      #pragma unroll
      for (int ni = 0; ni < 4; ++ni)
        bg[ni] = BsV[(wn + ni * 16 + (l & 15)) * 8 + (kb ^ sw)];
      #pragma unroll
      for (int mi = 0; mi < 4; ++mi)
        #pragma unroll
        for (int ni = 0; ni < 4; ++ni)
          acc[mi][ni] = __builtin_amdgcn_mfma_f32_16x16x32_bf16(af[mi], bg[ni], acc[mi][ni], 0, 0, 0);
    }
    __syncthreads();
  }

  const int r0 = bm + wm + (l >> 4) * 4;
  const int c0 = bn + wn + (l & 15);
  #pragma unroll
  for (int mi = 0; mi < 4; ++mi)
    #pragma unroll
    for (int ni = 0; ni < 4; ++ni) {
      const int col = c0 + ni * 16;
      #pragma unroll
      for (int j = 0; j < 4; ++j) {
        const float v = acc[mi][ni][j];
        const int row = r0 + mi * 16 + j;
        if (col < QW)
          Cq[(size_t)row * QW + col] = f2b(v * ATT_SCALE2);  // fold softmax scale
        else if (col - QW < AW)
          Ckva[(size_t)row * AW + (col - QW)] = f2b(v);
      }
    }
}

// ---------- fused RMSNorm(cols 0..511) + RoPE-k(cols 512..575), one wave per row ----------
__global__ __launch_bounds__(64) void k_rms_ropek(unsigned short* __restrict__ kva,
                                                  const float* __restrict__ w) {
  const int row = blockIdx.x;
  const int t = row & (NS - 1);
  const int lane = threadIdx.x;
  unsigned short* p = kva + (long)row * AW;

  short8 v = *(const short8*)(p + lane * 8);
  float f[8];
  float ss = 0.f;
  #pragma unroll
  for (int j = 0; j < 8; ++j) {
    f[j] = b2f((unsigned short)v[j]);
    ss += f[j] * f[j];
  }
  #pragma unroll
  for (int o2 = 1; o2 < 64; o2 <<= 1) ss += __shfl_xor(ss, o2, 64);
  const float sc = rsqrtf(ss / (float)RANK + 1e-6f);
  short8 ov;
  #pragma unroll
  for (int j = 0; j < 8; ++j)
    ov[j] = (short)f2b(f[j] * sc * w[lane * 8 + j]);
  *(short8*)(p + lane * 8) = ov;

  if (lane < 32) {
    const float invf = exp2f(-(float)lane * (LOG2_10000 / 32.0f));
    const float ang = (float)t * invf;
    float s, c;
    sincosf(ang, &s, &c);
    unsigned short* pp = p + RANK + 2 * lane;
    const float x0 = b2f(pp[0]), x1 = b2f(pp[1]);
    pp[0] = f2b(x0 * c - x1 * s);
    pp[1] = f2b(x0 * s + x1 * c);
  }
}

// ---------- MFMA flash attention: XCD-locality block remap ----------
// grid (8, NH, NB) = 256 blocks = 1/CU. Bijective remap: gid=(bx0+8h0+128b0);
// xcd = gid&7 (round-robin); the 4 (b,h) pairs 4*xcd..4*xcd+3 and their 8 bx
// blocks all land on XCD xcd -> each pair's K/V stream fetched ~once per XCD
// (was: 8 blocks of one pair spread across all 8 XCDs -> 2x HBM over-fetch).
// Per-block work = 34 tiles for any (bx,pair) -> balance invariant.
#define KBLK 64
#define KSL 24               // 16B slots per K row (192 bf16)
#define KSB (KBLK*KSL*16)    // one Ks buffer, bytes (24 KB)
#define VTS 72               // VT row stride (elems)
#define VBUF (DVAL*VTS)      // one VT buffer (elems)
#define PLS 72               // P row stride (elems)
#define QTILES (NS/128)      // 16
__global__ __launch_bounds__(512) void k_attn_mfma(
    const unsigned short* __restrict__ qg,
    const unsigned short* __restrict__ kvbg,
    const unsigned short* __restrict__ kvag,
    unsigned short* __restrict__ attg) {
  __shared__ short8 Ks[2 * KBLK * KSL];                        // 48 KB (dbuf)
  __shared__ __align__(16) unsigned short VT[2 * VBUF];        // 36 KB (dbuf)
  __shared__ __align__(16) unsigned short Pl[128 * PLS];       // 18 KB
  const int tid = threadIdx.x;
  const int l = tid & 63, w = tid >> 6;    // w 0..7
  const int g = l >> 4, r16 = l & 15;
  // XCD-locality bijection (see header comment)
  const int gid  = (int)(blockIdx.x + 8 * blockIdx.y + 128 * blockIdx.z);
  const int xcd  = gid & 7;
  const int jj_  = gid >> 3;                 // 0..31
  const int pair = 4 * xcd + (jj_ >> 3);     // 0..31
  const int bxn  = jj_ & 7;                  // 0..7
  const int h = pair & 15;
  const int b = pair >> 4;
  const unsigned short* q   = qg   + (size_t)b * NS * QW;
  const unsigned short* kvb = kvbg + (size_t)b * NS * BW;
  const unsigned short* kva = kvag + (size_t)b * NS * AW;
  unsigned short* att = attg + (size_t)b * NS * OW;

  // ---- staging geometry, constant per thread ----
  const unsigned short* kbs[3]; int kstp[3]; int kdo[3];
  #pragma unroll
  for (int i = 0; i < 3; ++i) {
    const int chunk = i * 512 + tid;
    const int row = chunk / KSL, p = chunk % KSL;
    const int s = (p & ~7) | ((p & 7) ^ (row & 7));
    const int d0 = s * 8;
    if (d0 < DNOPE) { kbs[i] = kvb + (size_t)row * BW + h * 256 + d0; kstp[i] = KBLK * BW; }
    else            { kbs[i] = kva + (size_t)row * AW + RANK + (d0 - DNOPE); kstp[i] = KBLK * AW; }
    kdo[i] = (i * 512 + (tid & ~63)) * 16;
  }
  const int vt_t = tid >> 3, vqd = tid & 7;
  const unsigned short* vbs = kvb + (size_t)vt_t * BW + h * 256 + DNOPE + vqd * 8;
  unsigned short* vwd = VT + (vqd * 8) * VTS + (vt_t ^ (vqd << 3));

  #pragma unroll 1
  for (int phase = 0; phase < 2; ++phase) {
    const int qt = phase ? (QTILES - 1 - bxn) : bxn;
    const int nt = 2 * qt + 2;
    const int qrow0 = qt * 128 + w * 16;

    // Q A-frags with fused RoPE on pe frags (f = 4,5); q already carries ATT_SCALE2
    short8 aq[6];
    {
      const unsigned short* qp = q + (size_t)(qrow0 + r16) * QW + h * 192 + g * 8;
      const float tpos = (float)(qrow0 + r16);
      #pragma unroll
      for (int f = 0; f < 6; ++f) {
        short8 v = *(const short8*)(qp + f * 32);
        if (f >= 4) {
          const int ibase = (f - 4) * 16 + g * 4;
          #pragma unroll
          for (int m = 0; m < 4; ++m) {
            const float invf = exp2f(-(float)(ibase + m) * (LOG2_10000 / 32.0f));
            float s_, c_;
            sincosf(tpos * invf, &s_, &c_);
            const float x0 = b2f((unsigned short)v[2 * m]);
            const float x1 = b2f((unsigned short)v[2 * m + 1]);
            v[2 * m]     = (short)f2b(x0 * c_ - x1 * s_);
            v[2 * m + 1] = (short)f2b(x0 * s_ + x1 * c_);
          }
        }
        aq[f] = v;
      }
    }
    f32x4 o[8] = {};
    float m_j[4], l_j[4];     // m_j: wave-uniform per row; l_j: LANE-PARTIAL sums
    #pragma unroll
    for (int j = 0; j < 4; ++j) { m_j[j] = -1e30f; l_j[j] = 0.f; }

    const unsigned short* kq0 = kbs[0];
    const unsigned short* kq1 = kbs[1];
    const unsigned short* kq2 = kbs[2];
    const unsigned short* vq  = vbs;

    // prologue: stage K_0 + V_0 into buffer 0
    gload16(kq0, (char*)Ks + kdo[0]); kq0 += kstp[0];
    gload16(kq1, (char*)Ks + kdo[1]); kq1 += kstp[1];
    gload16(kq2, (char*)Ks + kdo[2]); kq2 += kstp[2];
    {
      short8 vA = *(const short8*)(vq);
      short8 vB = *(const short8*)(vq + 64);
      #pragma unroll
      for (int jj = 0; jj < 8; ++jj) {
        vwd[jj * VTS] = (unsigned short)vA[jj];
        vwd[64 * VTS + jj * VTS] = (unsigned short)vB[jj];
      }
      vq += KBLK * BW;
    }
    __syncthreads();
    int cur = 0;

    for (int kt = 0; kt < nt; ++kt) {
      // (a) issue next-tile prefetch EARLY: K -> Ks[cur^1] (async), V -> regs
      const bool pref = (kt + 1 < nt);
      short8 vA, vB;
      if (pref) {
        char* kb1 = (char*)Ks + (cur ^ 1) * KSB;
        gload16(kq0, kb1 + kdo[0]); kq0 += kstp[0];
        gload16(kq1, kb1 + kdo[1]); kq1 += kstp[1];
        gload16(kq2, kb1 + kdo[2]); kq2 += kstp[2];
        vA = *(const short8*)(vq);
        vB = *(const short8*)(vq + 64);
        vq += KBLK * BW;
      }

      // (b) S = Q K^T from Ks[cur]  (already scaled via q)
      const short8* ksrc = Ks + cur * (KBLK * KSL);
      f32x4 sa[4] = {};
      __builtin_amdgcn_s_setprio(1);
      #pragma unroll
      for (int f = 0; f < 6; ++f) {
        #pragma unroll
        for (int n = 0; n < 4; ++n) {
          const int row = n * 16 + r16;
          const int s = f * 4 + g;
          const int phys = (s & ~7) | ((s & 7) ^ (row & 7));
          short8 bg = ksrc[row * KSL + phys];
          sa[n] = __builtin_amdgcn_mfma_f32_16x16x32_bf16(aq[f], bg, sa[n], 0, 0, 0);
        }
      }
      __builtin_amdgcn_s_setprio(0);

      // (c) softmax (log2 domain), lazy-max, lane-partial l
      const bool diag = (kt >= nt - 2);
      float pj[4][4];
      #pragma unroll
      for (int n = 0; n < 4; ++n) {
        const int key = kt * KBLK + n * 16 + r16;
        #pragma unroll
        for (int j = 0; j < 4; ++j) {
          float v = sa[n][j];
          if (diag && key > (qrow0 + g * 4 + j)) v = -1e30f;
          pj[n][j] = v;
        }
      }
      float mjl[4];
      #pragma unroll
      for (int j = 0; j < 4; ++j)
        mjl[j] = fmaxf(fmaxf(pj[0][j], pj[1][j]), fmaxf(pj[2][j], pj[3][j]));
      const bool myneed = (mjl[0] > m_j[0] + 8.f) | (mjl[1] > m_j[1] + 8.f) |
                          (mjl[2] > m_j[2] + 8.f) | (mjl[3] > m_j[3] + 8.f);
      if (__any(myneed)) {             // rare after first tile
        #pragma unroll
        for (int j = 0; j < 4; ++j) {
          float mx = mjl[j];
          #pragma unroll
          for (int o2 = 1; o2 < 16; o2 <<= 1) mx = fmaxf(mx, __shfl_xor(mx, o2, 64));
          const float mn = fmaxf(m_j[j], mx);
          const float c = exp2f(m_j[j] - mn);
          l_j[j] *= c;
          #pragma unroll
          for (int n8 = 0; n8 < 8; ++n8) o[n8][j] *= c;
          m_j[j] = mn;
        }
      }
      #pragma unroll
      for (int j = 0; j < 4; ++j) {
        float p0 = exp2f(pj[0][j] - m_j[j]);
        float p1 = exp2f(pj[1][j] - m_j[j]);
        float p2 = exp2f(pj[2][j] - m_j[j]);
        float p3 = exp2f(pj[3][j] - m_j[j]);
        l_j[j] += (p0 + p1) + (p2 + p3);   // lane-partial; reduced in epilogue
        const int prow = w * 16 + g * 4 + j;
        const int cswz = r16 ^ ((g >> 1) << 3);    // col bit3 ^= row bit3
        const unsigned pk01 = cvtpk(p0, p1);
        const unsigned pk23 = cvtpk(p2, p3);
        Pl[prow * PLS +  0 + cswz] = (unsigned short)pk01;
        Pl[prow * PLS + 16 + cswz] = (unsigned short)(pk01 >> 16);
        Pl[prow * PLS + 32 + cswz] = (unsigned short)pk23;
        Pl[prow * PLS + 48 + cswz] = (unsigned short)(pk23 >> 16);
      }

      // (d) write prefetched V into the alternate buffer
      if (pref) {
        unsigned short* dst = vwd + (cur ^ 1) * VBUF;
        #pragma unroll
        for (int jj = 0; jj < 8; ++jj) {
          dst[jj * VTS] = (unsigned short)vA[jj];
          dst[64 * VTS + jj * VTS] = (unsigned short)vB[jj];
        }
      }

      // (e) O += P V from VT[cur]  (Pl rows wave-private; read block ^= r16>>3)
      const int hb = r16 >> 3;
      const unsigned short* vbase = VT + cur * VBUF;
      #pragma unroll
      for (int kk = 0; kk < 2; ++kk) {
        short8 pa = *(const short8*)&Pl[(w * 16 + r16) * PLS +
                                        ((((kk * 4 + g) ^ hb) & 7) << 3)];
        __builtin_amdgcn_s_setprio(1);
        #pragma unroll
        for (int n8 = 0; n8 < 8; ++n8) {
          const int blk = (kk * 4 + g) ^ ((n8 * 2 + hb) & 7);
          short8 vb = *(const short8*)&vbase[(n8 * 16 + r16) * VTS + blk * 8];
          o[n8] = __builtin_amdgcn_mfma_f32_16x16x32_bf16(pa, vb, o[n8], 0, 0, 0);
        }
        __builtin_amdgcn_s_setprio(0);
      }

      // (f) single barrier: K_{t+1} gloads drained, VT[cur^1] writes visible
      __syncthreads();
      cur ^= 1;
    }

    // epilogue: reduce lane-partial l across the 16 lanes of each row, then store
    #pragma unroll
    for (int j = 0; j < 4; ++j) {
      float ls = l_j[j];
      #pragma unroll
      for (int o2 = 1; o2 < 16; o2 <<= 1) ls += __shfl_xor(ls, o2, 64);
      const float inv = 1.0f / ls;
      const size_t rowoff = (size_t)(qrow0 + g * 4 + j) * OW + h * DVAL;
      #pragma unroll
      for (int n8 = 0; n8 < 8; ++n8)
        att[rowoff + n8 * 16 + r16] = f2b(o[n8][j] * inv);
    }
    __syncthreads();                   // protect next phase's prologue staging
  }
}

extern "C" void kernel_launch(void* const* d_in, const int* in_sizes, int n_in,
                              void* d_out, int out_size, void* d_ws, size_t ws_size,
                              hipStream_t stream) {
  const float* x      = (const float*)d_in[0];
  const float* wq     = (const float*)d_in[1];
  const float* wkv_a  = (const float*)d_in[2];
  const float* w_norm = (const float*)d_in[3];
  const float* wkv_b  = (const float*)d_in[4];
  const float* wo     = (const float*)d_in[5];
  float* out = (float*)d_out;

  unsigned short* wqT   = (unsigned short*)d_ws;           // 3072 x 2048
  unsigned short* wkvaT = wqT   + (long)QW * ND;           // 640  x 2048 (contiguous after wqT)
  unsigned short* wkvbT = wkvaT + (long)AWPAD * ND;        // 4096 x 512
  unsigned short* woT   = wkvbT + (long)BW * RANK;         // 2048 x 2048
  unsigned short* xb2   = woT   + (long)ND * OW;           // 2 x 2048 x 2048
  unsigned short* q2    = xb2   + (long)NB * NS * ND;      // 2 x 2048 x 3072
  unsigned short* kva2  = q2    + (long)NB * NS * QW;      // 2 x 2048 x 576
  unsigned short* kvb2  = kva2  + (long)NB * NS * AW;      // 2 x 2048 x 4096
  unsigned short* att2  = xb2;                             // alias (xb2 dead by attn)

  k_transpose<<<dim3(ND / 32, QW / 32),    dim3(256), 0, stream>>>(wq,    wqT,   ND,  QW);
  k_transpose<<<dim3(ND / 32, AWPAD / 32), dim3(256), 0, stream>>>(wkv_a, wkvaT, ND,  AW);
  k_transpose<<<dim3(RANK / 32, BW / 32),  dim3(256), 0, stream>>>(wkv_b, wkvbT, RANK, BW);
  k_transpose<<<dim3(OW / 32, ND / 32),    dim3(256), 0, stream>>>(wo,    woT,   OW,  ND);

  k_cvt<<<dim3((NB * NS * ND) / 1024), dim3(256), 0, stream>>>(x, xb2);
  gemm_fused_qkva<<<dim3((QW + AWPAD) / 128, (NB * NS) / 128), dim3(256), 0, stream>>>(
      xb2, wqT, q2, kva2, ND);
  k_rms_ropek<<<dim3(NB * NS), dim3(64), 0, stream>>>(kva2, w_norm);
  gemm_bf16<unsigned short><<<dim3(BW / 128, (NB * NS) / 128), dim3(256), 0, stream>>>(
      kva2, wkvbT, kvb2, NB * NS, BW, RANK, AW);
  k_attn_mfma<<<dim3(QTILES / 2, NH, NB), dim3(512), 0, stream>>>(q2, kvb2, kva2, att2);
  gemm_bf16<float><<<dim3(ND / 128, (NB * NS) / 128), dim3(256), 0, stream>>>(
      att2, woT, out, NB * NS, ND, OW, OW);
}